// Round 2
// baseline (829.275 us; speedup 1.0000x reference)
//
#include <hip/hip_runtime.h>
#include <math.h>

#define NN 100000
#define EE 1000000
#define DD 128
#define CLS 64

#define NB 196        // destination buckets per view (512 nodes each)
#define CHUNK 4096    // edges per partition workgroup
#define NCH 245       // ceil(EE / CHUNK)
#define SLOTS (3 * NB * NCH)   // 144060
#define CAPB 8192     // LDS record cache in buildB

typedef short bf16x8 __attribute__((ext_vector_type(8)));
typedef float f32x4 __attribute__((ext_vector_type(4)));

static __device__ __forceinline__ short f2bf(float f) {
  union { float f; unsigned u; } v; v.f = f;
  unsigned r = v.u + 0x7FFF + ((v.u >> 16) & 1);   // RNE
  return (short)(r >> 16);
}
static __device__ __forceinline__ unsigned pack2(float a, float b) {
  return ((unsigned)(unsigned short)f2bf(b) << 16) | (unsigned short)f2bf(a);
}
static __device__ __forceinline__ float bf_lo(unsigned u) {
  union { unsigned u; float f; } v; v.u = u << 16; return v.f;
}
static __device__ __forceinline__ float bf_hi(unsigned u) {
  union { unsigned u; float f; } v; v.u = u & 0xffff0000u; return v.f;
}

// ---------------- PE add: h = bf16(x + pe), 8 elems/thread ----------------
__global__ __launch_bounds__(256) void pe_kernel(const float* __restrict__ x,
                                                 const float* __restrict__ pe,
                                                 short* __restrict__ h) {
  int idx8 = blockIdx.x * 256 + threadIdx.x;   // grid 6250 -> 1.6M exact
  int d0 = (idx8 & 15) * 8;
  float4 a = *(const float4*)&x[(size_t)idx8 * 8];
  float4 b = *(const float4*)&x[(size_t)idx8 * 8 + 4];
  float4 pa = *(const float4*)&pe[d0];
  float4 pb = *(const float4*)&pe[d0 + 4];
  int4 o;
  o.x = pack2(a.x + pa.x, a.y + pa.y);
  o.y = pack2(a.z + pa.z, a.w + pa.w);
  o.z = pack2(b.x + pb.x, b.y + pb.y);
  o.w = pack2(b.z + pb.z, b.w + pb.w);
  *(int4*)&h[(size_t)idx8 * 8] = o;
}

// ---------------- weight prep ----------------
__global__ __launch_bounds__(256) void wprep_kernel(const float* __restrict__ Wmi,
                                                    const float* __restrict__ Wmo,
                                                    const float* __restrict__ Wsh,
                                                    const float* __restrict__ Wu,
                                                    short* __restrict__ Wcat) {
  int idx = blockIdx.x * 256 + threadIdx.x;   // grid 384 -> 98304 exact
  int l = idx / 49152;
  int r = idx - l * 49152;
  int j = r >> 7, k = r & 127;
  float v;
  if (j < 128)      v = Wmi[l*16384 + j*128 + k] + Wsh[l*16384 + j*128 + k];
  else if (j < 256) v = Wmo[l*16384 + (j-128)*128 + k] + Wsh[l*16384 + (j-128)*128 + k];
  else              v = Wu[l*16384 + (j-256)*128 + k];
  Wcat[idx] = f2bf(v);
}

// ---------------- partition phase A: per-chunk bucket histogram ----------------
__global__ __launch_bounds__(256) void countA_kernel(const int* __restrict__ ei0,
                                                     const int* __restrict__ ei1,
                                                     const int* __restrict__ ei2,
                                                     int* __restrict__ counts) {
  __shared__ int c[NB];
  int v = blockIdx.y, ch = blockIdx.x, tid = threadIdx.x;
  const int* dstp = ((v == 0) ? ei0 : (v == 1) ? ei1 : ei2) + EE;
  for (int i = tid; i < NB; i += 256) c[i] = 0;
  __syncthreads();
  int s = ch * CHUNK, e = (s + CHUNK < EE) ? s + CHUNK : EE;
  for (int i = s + tid; i < e; i += 256) atomicAdd(&c[dstp[i] >> 9], 1);
  __syncthreads();
  for (int b = tid; b < NB; b += 256) counts[(v * NB + b) * NCH + ch] = c[b];
}

// ---------------- scan (generalized length n) ----------------
__global__ __launch_bounds__(256) void scan1_kernel(const int* __restrict__ counts,
                                                    int* __restrict__ S,
                                                    int* __restrict__ bsums, int n) {
  __shared__ int sd[256];
  int t = threadIdx.x;
  int base = blockIdx.x * 1024 + t * 4;
  int4 v = make_int4(0, 0, 0, 0);
  if (base + 3 < n) {
    v = *(const int4*)&counts[base];
  } else {
    if (base + 0 < n) v.x = counts[base + 0];
    if (base + 1 < n) v.y = counts[base + 1];
    if (base + 2 < n) v.z = counts[base + 2];
    if (base + 3 < n) v.w = counts[base + 3];
  }
  int ts = v.x + v.y + v.z + v.w;
  sd[t] = ts;
  __syncthreads();
  for (int off = 1; off < 256; off <<= 1) {
    int xel = (t >= off) ? sd[t - off] : 0;
    __syncthreads();
    sd[t] += xel;
    __syncthreads();
  }
  int excl = sd[t] - ts;
  int o0 = excl, o1 = o0 + v.x, o2 = o1 + v.y, o3 = o2 + v.z;
  if (base + 0 < n) S[base + 0] = o0;
  if (base + 1 < n) S[base + 1] = o1;
  if (base + 2 < n) S[base + 2] = o2;
  if (base + 3 < n) S[base + 3] = o3;
  if (t == 255) bsums[blockIdx.x] = sd[255];
}

__global__ void scan2_kernel(int* __restrict__ bsums, int nb) {
  __shared__ int sd[512];
  int t = threadIdx.x;
  int v = (t < nb) ? bsums[t] : 0;
  sd[t] = v;
  __syncthreads();
  for (int off = 1; off < 512; off <<= 1) {
    int xel = (t >= off) ? sd[t - off] : 0;
    __syncthreads();
    sd[t] += xel;
    __syncthreads();
  }
  if (t < nb) bsums[t] = sd[t] - v;
}

__global__ __launch_bounds__(256) void scan3_kernel(int* __restrict__ S,
                                                    const int* __restrict__ bsums, int n) {
  int i = blockIdx.x * 256 + threadIdx.x;
  if (i < n) S[i] += bsums[i >> 10];
}

// ---------------- partition phase A: scatter into bucket-major runs ----------------
__global__ __launch_bounds__(256) void partA_kernel(const int* __restrict__ ei0,
                                                    const int* __restrict__ ei1,
                                                    const int* __restrict__ ei2,
                                                    const float* __restrict__ ew0,
                                                    const float* __restrict__ ew1,
                                                    const float* __restrict__ ew2,
                                                    const int* __restrict__ S,
                                                    int2* __restrict__ binned) {
  __shared__ int cur[NB];
  int v = blockIdx.y, ch = blockIdx.x, tid = threadIdx.x;
  const int* ei = (v == 0) ? ei0 : (v == 1) ? ei1 : ei2;
  const float* ew = (v == 0) ? ew0 : (v == 1) ? ew1 : ew2;
  for (int b = tid; b < NB; b += 256) cur[b] = S[(v * NB + b) * NCH + ch];
  __syncthreads();
  int s = ch * CHUNK, e = (s + CHUNK < EE) ? s + CHUNK : EE;
  for (int i = s + tid; i < e; i += 256) {
    int src = ei[i];
    int dst = ei[EE + i];
    float w = ew[i];
    int b = dst >> 9;
    int pos = atomicAdd(&cur[b], 1);
    binned[pos] = make_int2(src | ((dst & 511) << 17), __float_as_int(w));
  }
}

// ---------------- phase B: per-bucket local CSR + offs ----------------
__global__ __launch_bounds__(256) void buildB_kernel(const int2* __restrict__ binned,
                                                     const int* __restrict__ S,
                                                     unsigned* __restrict__ csr4,
                                                     int* __restrict__ offs) {
  __shared__ int2 recs[CAPB];   // 64 KB
  __shared__ int cnt[512];
  __shared__ int pref[512];
  __shared__ int sd[256];
  int gb = blockIdx.x, tid = threadIdx.x;
  int v = gb / NB, b = gb - v * NB;
  int base = S[gb * NCH];
  int next = (gb == 3 * NB - 1) ? 3 * EE : S[(gb + 1) * NCH];
  int n = next - base;
  for (int i = tid; i < 512; i += 256) cnt[i] = 0;
  int m = n < CAPB ? n : CAPB;
  for (int i = tid; i < m; i += 256) recs[i] = binned[base + i];
  __syncthreads();
  for (int i = tid; i < n; i += 256) {
    int2 r = (i < CAPB) ? recs[i] : binned[base + i];
    atomicAdd(&cnt[(r.x >> 17) & 511], 1);
  }
  __syncthreads();
  // exclusive scan over 512 with 256 threads (pairwise + Hillis-Steele)
  int c0 = cnt[2 * tid], c1 = cnt[2 * tid + 1];
  int ssum = c0 + c1;
  sd[tid] = ssum;
  __syncthreads();
  for (int off = 1; off < 256; off <<= 1) {
    int x = (tid >= off) ? sd[tid - off] : 0;
    __syncthreads();
    sd[tid] += x;
    __syncthreads();
  }
  int excl = sd[tid] - ssum;
  pref[2 * tid] = excl;
  pref[2 * tid + 1] = excl + c0;
  __syncthreads();
  int node0 = b * 512;
  for (int i = tid; i < 512; i += 256) {
    int node = node0 + i;
    if (node < NN) offs[v * NN + node] = base + pref[i];
  }
  if (gb == 0 && tid == 0) offs[3 * NN] = 3 * EE;
  for (int i = tid; i < 512; i += 256) cnt[i] = pref[i];   // cursors
  __syncthreads();
  for (int i = tid; i < n; i += 256) {
    int2 r = (i < CAPB) ? recs[i] : binned[base + i];
    int nl = (r.x >> 17) & 511;
    int p = atomicAdd(&cnt[nl], 1);
    float w = __int_as_float(r.y);
    unsigned wb = (unsigned)(unsigned short)f2bf(w);   // positive -> 15 bits
    csr4[base + p] = (wb << 17) | (unsigned)(r.x & 0x1FFFF);
  }
}

// ---------------- fused 3-view GEMM via bf16 MFMA ----------------
// A-tile loaded once, reused across 3 views. Epilogue stages C (bf16) into
// the free Bs tile, then does coalesced int4 stores (8x fewer store insts).
#define LW 136
__global__ __launch_bounds__(256) void mm_mfma(const short* __restrict__ H,
                                               const short* __restrict__ WcatL,
                                               short* __restrict__ tAll) {
  __shared__ short As[128 * LW];
  __shared__ short Bs[128 * LW];
  int tid = threadIdx.x;
  int rowbase = blockIdx.x * 128;

  for (int idx = tid; idx < 2048; idx += 256) {
    int r = idx >> 4, c8 = (idx & 15) * 8;
    int gr = rowbase + r; if (gr >= NN) gr = NN - 1;
    *(int4*)&As[r * LW + c8] = *(const int4*)&H[(size_t)gr * 128 + c8];
  }

  int w = tid >> 6, lane = tid & 63;
  int wr = (w >> 1) * 64, wc = (w & 1) * 64;
  int lrow = lane & 15, quad = lane >> 4;

  for (int view = 0; view < 3; ++view) {
    __syncthreads();   // As ready / prior C-stores done reading Bs
    for (int idx = tid; idx < 2048; idx += 256) {
      int r = idx >> 4, c8 = (idx & 15) * 8;
      *(int4*)&Bs[r * LW + c8] = *(const int4*)&WcatL[(view * 128 + r) * 128 + c8];
    }
    __syncthreads();

    f32x4 acc[4][4];
#pragma unroll
    for (int mi = 0; mi < 4; ++mi)
#pragma unroll
      for (int ni = 0; ni < 4; ++ni) acc[mi][ni] = (f32x4){0.f, 0.f, 0.f, 0.f};

#pragma unroll
    for (int k0 = 0; k0 < 128; k0 += 32) {
      bf16x8 a[4], b[4];
#pragma unroll
      for (int mi = 0; mi < 4; ++mi)
        a[mi] = *(const bf16x8*)&As[(wr + mi * 16 + lrow) * LW + k0 + quad * 8];
#pragma unroll
      for (int ni = 0; ni < 4; ++ni)
        b[ni] = *(const bf16x8*)&Bs[(wc + ni * 16 + lrow) * LW + k0 + quad * 8];
#pragma unroll
      for (int mi = 0; mi < 4; ++mi)
#pragma unroll
        for (int ni = 0; ni < 4; ++ni)
          acc[mi][ni] = __builtin_amdgcn_mfma_f32_16x16x32_bf16(a[mi], b[ni], acc[mi][ni], 0, 0, 0);
    }

    __syncthreads();   // all waves done ds_read'ing Bs -> safe to overwrite
#pragma unroll
    for (int mi = 0; mi < 4; ++mi)
#pragma unroll
      for (int ni = 0; ni < 4; ++ni)
#pragma unroll
        for (int r = 0; r < 4; ++r) {
          int rl = wr + mi * 16 + quad * 4 + r;
          int cl = wc + ni * 16 + lrow;
          Bs[rl * LW + cl] = f2bf(acc[mi][ni][r]);
        }
    __syncthreads();   // staged C visible to all threads

    short* out = tAll + (size_t)view * ((size_t)NN * 128);
    for (int idx = tid; idx < 2048; idx += 256) {
      int r = idx >> 4, c8 = (idx & 15) * 8;
      int row = rowbase + r;
      if (row < NN)
        *(int4*)&out[(size_t)row * 128 + c8] = *(const int4*)&Bs[r * LW + c8];
    }
  }
}

// ---------------- gather-aggregate + combine + residual + leaky_relu ----------------
// one wave per node; two 32-lane halves each own one edge of a pair.
// Each lane owns 4 features (8B dwordx2 gather). Records come via uniform
// (scalar) loads; halves combined with one shfl_xor(32) at the end.
__global__ __launch_bounds__(256) void agg_kernel(
    const short* __restrict__ tAll, const unsigned* __restrict__ csr4,
    const int* __restrict__ offs, const short* __restrict__ h_prev,
    const float* __restrict__ b_mi, const float* __restrict__ b_mo,
    const float* __restrict__ b_si, const float* __restrict__ b_so,
    const float* __restrict__ b_u, const float* __restrict__ Cin,
    const float* __restrict__ Cout, const float* __restrict__ Call,
    const float* __restrict__ cst, short* __restrict__ h_out) {
  int gid = blockIdx.x * 256 + threadIdx.x;
  int v = gid >> 6;
  int lane = gid & 63;
  int m = lane & 31;
  int hh = lane >> 5;          // which edge of the pair this half handles
  int f0 = m * 4;              // this lane's 4 features
  float a[3][4];

#pragma unroll
  for (int view = 0; view < 3; ++view) {
    const short* t = tAll + (size_t)view * ((size_t)NN * 128);
    int s = offs[view * NN + v];
    int e = offs[view * NN + v + 1];
    int cnt = e - s;
    int npair = cnt >> 1;
    float a0 = 0.f, a1 = 0.f, a2 = 0.f, a3 = 0.f;
    int i = 0;
    for (; i + 1 < npair; i += 2) {
      unsigned q0 = csr4[s + 2 * i + 0];
      unsigned q1 = csr4[s + 2 * i + 1];
      unsigned q2 = csr4[s + 2 * i + 2];
      unsigned q3 = csr4[s + 2 * i + 3];
      unsigned rA = hh ? q1 : q0;
      unsigned rB = hh ? q3 : q2;
      float wA = __uint_as_float((rA >> 17) << 16);
      float wB = __uint_as_float((rB >> 17) << 16);
      uint2 uA = *(const uint2*)&t[(size_t)(rA & 0x1FFFF) * 128 + f0];
      uint2 uB = *(const uint2*)&t[(size_t)(rB & 0x1FFFF) * 128 + f0];
      a0 += wA * bf_lo(uA.x) + wB * bf_lo(uB.x);
      a1 += wA * bf_hi(uA.x) + wB * bf_hi(uB.x);
      a2 += wA * bf_lo(uA.y) + wB * bf_lo(uB.y);
      a3 += wA * bf_hi(uA.y) + wB * bf_hi(uB.y);
    }
    for (; i < npair; ++i) {
      unsigned q0 = csr4[s + 2 * i + 0];
      unsigned q1 = csr4[s + 2 * i + 1];
      unsigned rA = hh ? q1 : q0;
      float wA = __uint_as_float((rA >> 17) << 16);
      uint2 uA = *(const uint2*)&t[(size_t)(rA & 0x1FFFF) * 128 + f0];
      a0 += wA * bf_lo(uA.x);
      a1 += wA * bf_hi(uA.x);
      a2 += wA * bf_lo(uA.y);
      a3 += wA * bf_hi(uA.y);
    }
    if (cnt & 1) {
      unsigned r0 = csr4[e - 1];
      float w0 = __uint_as_float((r0 >> 17) << 16);
      uint2 u0 = *(const uint2*)&t[(size_t)(r0 & 0x1FFFF) * 128 + f0];
      if (hh == 0) {
        a0 += w0 * bf_lo(u0.x);
        a1 += w0 * bf_hi(u0.x);
        a2 += w0 * bf_lo(u0.y);
        a3 += w0 * bf_hi(u0.y);
      }
    }
    a[view][0] = a0; a[view][1] = a1; a[view][2] = a2; a[view][3] = a3;
  }

  // combine the two halves
#pragma unroll
  for (int view = 0; view < 3; ++view)
#pragma unroll
    for (int k = 0; k < 4; ++k)
      a[view][k] += __shfl_xor(a[view][k], 32);

  float ci = Cin[v], co = Cout[v], ca = Call[v];
  float4 bi = *(const float4*)&b_mi[f0];
  float4 bsi4 = *(const float4*)&b_si[f0];
  float4 bo = *(const float4*)&b_mo[f0];
  float4 bso4 = *(const float4*)&b_so[f0];
  float4 bu = *(const float4*)&b_u[f0];
  float4 cs = *(const float4*)&cst[(size_t)v * 128 + f0];
  uint2 hp = *(const uint2*)&h_prev[(size_t)v * 128 + f0];

  float g0 = ca * (a[2][0] + bu.x) + ci * (a[0][0] + bi.x + bsi4.x) +
             co * (a[1][0] + bo.x + bso4.x) + cs.x + bf_lo(hp.x);
  float g1 = ca * (a[2][1] + bu.y) + ci * (a[0][1] + bi.y + bsi4.y) +
             co * (a[1][1] + bo.y + bso4.y) + cs.y + bf_hi(hp.x);
  float g2 = ca * (a[2][2] + bu.z) + ci * (a[0][2] + bi.z + bsi4.z) +
             co * (a[1][2] + bo.z + bso4.z) + cs.z + bf_lo(hp.y);
  float g3 = ca * (a[2][3] + bu.w) + ci * (a[0][3] + bi.w + bsi4.w) +
             co * (a[1][3] + bo.w + bso4.w) + cs.w + bf_hi(hp.y);
  g0 = g0 > 0.f ? g0 : 0.01f * g0;
  g1 = g1 > 0.f ? g1 : 0.01f * g1;
  g2 = g2 > 0.f ? g2 : 0.01f * g2;
  g3 = g3 > 0.f ? g3 : 0.01f * g3;
  if (hh == 0) {
    uint2 o;
    o.x = pack2(g0, g1);
    o.y = pack2(g2, g3);
    *(uint2*)&h_out[(size_t)v * 128 + f0] = o;
  }
}

// ---------------- fused decoder ----------------
__global__ __launch_bounds__(256) void dec_kernel(const short* __restrict__ h,
                                                  const float* __restrict__ Wd1,
                                                  const float* __restrict__ bd1,
                                                  const float* __restrict__ Wd2,
                                                  const float* __restrict__ bd2,
                                                  float* __restrict__ out_logp,
                                                  float* __restrict__ out_emb) {
  __shared__ float Hs[32 * 128];
  __shared__ float W1t[64 * 66];
  __shared__ float W2t[64 * 66];
  __shared__ float Zs[32 * 68];
  int tid = threadIdx.x;
  int base = blockIdx.x * 32;

  for (int idx = tid; idx < 2048; idx += 256) {
    unsigned u = *(const unsigned*)&h[(size_t)base * 128 + idx * 2];
    Hs[idx * 2] = bf_lo(u);
    Hs[idx * 2 + 1] = bf_hi(u);
  }
  for (int idx = tid; idx < 4096; idx += 256) {
    int c = idx >> 6, k = idx & 63;
    W2t[k * 66 + c] = Wd2[idx];
  }

  int j = tid & 63;
  int rg = tid >> 6;
  float zacc[8];
#pragma unroll
  for (int r = 0; r < 8; ++r) zacc[r] = 0.f;

  for (int kk = 0; kk < 128; kk += 64) {
    __syncthreads();
    for (int idx = tid; idx < 4096; idx += 256) {
      int jj = idx >> 6, k = idx & 63;
      W1t[k * 66 + jj] = Wd1[jj * 128 + kk + k];
    }
    __syncthreads();
    for (int k = 0; k < 64; ++k) {
      float w = W1t[k * 66 + j];
#pragma unroll
      for (int r = 0; r < 8; ++r) zacc[r] += Hs[(rg * 8 + r) * 128 + kk + k] * w;
    }
  }
  float b1 = bd1[j];
#pragma unroll
  for (int r = 0; r < 8; ++r) {
    float z = zacc[r] + b1;
    Zs[(rg * 8 + r) * 68 + j] = z > 0.f ? z : 0.f;
  }
  __syncthreads();

  float b2 = bd2[j];
  float lg[8];
#pragma unroll
  for (int i = 0; i < 8; ++i) lg[i] = b2;
  for (int k = 0; k < 64; ++k) {
    float w = W2t[k * 66 + j];
#pragma unroll
    for (int i = 0; i < 8; ++i) lg[i] += Zs[(rg + 4 * i) * 68 + k] * w;
  }

#pragma unroll
  for (int i = 0; i < 8; ++i) {
    float m = lg[i];
    for (int d = 1; d < 64; d <<= 1) m = fmaxf(m, __shfl_xor(m, d));
    float s = expf(lg[i] - m);
    for (int d = 1; d < 64; d <<= 1) s += __shfl_xor(s, d);
    float lp = lg[i] - m - logf(s);
    out_logp[(size_t)(base + rg + 4 * i) * 64 + j] = lp;
  }

#pragma unroll
  for (int i = 0; i < 8; ++i) {
    int r = rg + 4 * i;
    float v1 = Hs[r * 128 + j];
    float v2 = Hs[r * 128 + 64 + j];
    float ss = v1 * v1 + v2 * v2;
    for (int d = 1; d < 64; d <<= 1) ss += __shfl_xor(ss, d);
    float nrm = sqrtf(ss);
    float sc = 1.f / fmaxf(nrm, 1e-12f);
    size_t o = (size_t)(base + r) * 128;
    out_emb[o + j] = v1 * sc;
    out_emb[o + 64 + j] = v2 * sc;
  }
}

extern "C" void kernel_launch(void* const* d_in, const int* in_sizes, int n_in,
                              void* d_out, int out_size, void* d_ws, size_t ws_size,
                              hipStream_t stream) {
  const float* x   = (const float*)d_in[0];
  const int* eiI   = (const int*)d_in[1];
  const float* ewI = (const float*)d_in[2];
  const int* eiO   = (const int*)d_in[3];
  const float* ewO = (const float*)d_in[4];
  const int* eiU   = (const int*)d_in[5];
  const float* ewU = (const float*)d_in[6];
  const float* pe  = (const float*)d_in[7];
  const float* Wmi = (const float*)d_in[8];
  const float* Wmo = (const float*)d_in[9];
  const float* Wsh = (const float*)d_in[10];
  const float* Wu  = (const float*)d_in[11];
  const float* bmi = (const float*)d_in[12];
  const float* bmo = (const float*)d_in[13];
  const float* bsi = (const float*)d_in[14];
  const float* bso = (const float*)d_in[15];
  const float* bu  = (const float*)d_in[16];
  const float* Cin = (const float*)d_in[17];
  const float* Cou = (const float*)d_in[18];
  const float* Cal = (const float*)d_in[19];
  const float* cst = (const float*)d_in[20];
  const float* Wd1 = (const float*)d_in[21];
  const float* bd1 = (const float*)d_in[22];
  const float* Wd2 = (const float*)d_in[23];
  const float* bd2 = (const float*)d_in[24];

  const size_t ND = (size_t)NN * DD;   // 12,800,000
  short* wsS = (short*)d_ws;
  short* hA   = wsS;                    // ND shorts
  short* hB   = hA + ND;                // ND
  short* tAll = hB + ND;                // 3*ND
  short* Wcat = tAll + 3 * ND;          // 98304 shorts (total so far = even # shorts)
  int2* binned   = (int2*)(Wcat + 98304);          // 3E int2 (24 MB)
  unsigned* csr4 = (unsigned*)(binned + (size_t)3 * EE); // 3E uint (12 MB)
  int* S      = (int*)(csr4 + (size_t)3 * EE);     // SLOTS ints
  int* bsums  = S + SLOTS + 4;                     // scan block sums (<=512)
  int* offs   = bsums + 512;                       // 3N+1

  pe_kernel<<<6250, 256, 0, stream>>>(x, pe, hA);
  wprep_kernel<<<384, 256, 0, stream>>>(Wmi, Wmo, Wsh, Wu, Wcat);

  dim3 chGrid(NCH, 3);
  countA_kernel<<<chGrid, 256, 0, stream>>>(eiI, eiO, eiU, S);   // S holds raw counts first
  const int nb1 = (SLOTS + 1023) / 1024;   // 141
  scan1_kernel<<<nb1, 256, 0, stream>>>(S, S, bsums, SLOTS);     // in-place exclusive (block-local)
  scan2_kernel<<<1, 512, 0, stream>>>(bsums, nb1);
  scan3_kernel<<<(SLOTS + 255) / 256, 256, 0, stream>>>(S, bsums, SLOTS);
  partA_kernel<<<chGrid, 256, 0, stream>>>(eiI, eiO, eiU, ewI, ewO, ewU, S, binned);
  buildB_kernel<<<3 * NB, 256, 0, stream>>>(binned, S, csr4, offs);

  const short* hin = hA;
  short* hout = hB;
  dim3 mmGrid((NN + 127) / 128);   // 782 blocks, view loop inside
  for (int l = 0; l < 2; ++l) {
    mm_mfma<<<mmGrid, 256, 0, stream>>>(hin, Wcat + l * 49152, tAll);
    agg_kernel<<<25000, 256, 0, stream>>>(tAll, csr4, offs, hin,
                                          bmi + l * DD, bmo + l * DD, bsi + l * DD,
                                          bso + l * DD, bu + l * DD, Cin + l * NN,
                                          Cou + l * NN, Cal + l * NN,
                                          cst + (size_t)l * NN * DD, hout);
    short* tmp = (short*)hin;
    hin = hout;
    hout = tmp;
  }

  float* out_logp = (float*)d_out;
  float* out_emb = out_logp + (size_t)NN * CLS;
  dec_kernel<<<3125, 256, 0, stream>>>(hin, Wd1, bd1, Wd2, bd2, out_logp, out_emb);
}

// Round 3
// 820.954 us; speedup vs baseline: 1.0101x; 1.0101x over previous
//
#include <hip/hip_runtime.h>
#include <math.h>

#define NN 100000
#define EE 1000000
#define DD 128
#define CLS 64

#define NB 196        // destination buckets per view (512 nodes each)
#define CHUNK 4096    // edges per partition workgroup
#define NCH 245       // ceil(EE / CHUNK)
#define SLOTS (3 * NB * NCH)   // 144060
#define CAPB 8192     // LDS record cache in buildB

typedef short bf16x8 __attribute__((ext_vector_type(8)));
typedef float f32x4 __attribute__((ext_vector_type(4)));

static __device__ __forceinline__ short f2bf(float f) {
  union { float f; unsigned u; } v; v.f = f;
  unsigned r = v.u + 0x7FFF + ((v.u >> 16) & 1);   // RNE
  return (short)(r >> 16);
}
static __device__ __forceinline__ unsigned pack2(float a, float b) {
  return ((unsigned)(unsigned short)f2bf(b) << 16) | (unsigned short)f2bf(a);
}
static __device__ __forceinline__ float bf_lo(unsigned u) {
  union { unsigned u; float f; } v; v.u = u << 16; return v.f;
}
static __device__ __forceinline__ float bf_hi(unsigned u) {
  union { unsigned u; float f; } v; v.u = u & 0xffff0000u; return v.f;
}
static __device__ __forceinline__ float bfs(short s) {
  union { unsigned u; float f; } v; v.u = ((unsigned)(unsigned short)s) << 16; return v.f;
}

// ---------------- PE add: h = bf16(x + pe), 8 elems/thread ----------------
__global__ __launch_bounds__(256) void pe_kernel(const float* __restrict__ x,
                                                 const float* __restrict__ pe,
                                                 short* __restrict__ h) {
  int idx8 = blockIdx.x * 256 + threadIdx.x;   // grid 6250 -> 1.6M exact
  int d0 = (idx8 & 15) * 8;
  float4 a = *(const float4*)&x[(size_t)idx8 * 8];
  float4 b = *(const float4*)&x[(size_t)idx8 * 8 + 4];
  float4 pa = *(const float4*)&pe[d0];
  float4 pb = *(const float4*)&pe[d0 + 4];
  int4 o;
  o.x = pack2(a.x + pa.x, a.y + pa.y);
  o.y = pack2(a.z + pa.z, a.w + pa.w);
  o.z = pack2(b.x + pb.x, b.y + pb.y);
  o.w = pack2(b.z + pb.z, b.w + pb.w);
  *(int4*)&h[(size_t)idx8 * 8] = o;
}

// ---------------- weight prep ----------------
__global__ __launch_bounds__(256) void wprep_kernel(const float* __restrict__ Wmi,
                                                    const float* __restrict__ Wmo,
                                                    const float* __restrict__ Wsh,
                                                    const float* __restrict__ Wu,
                                                    short* __restrict__ Wcat) {
  int idx = blockIdx.x * 256 + threadIdx.x;   // grid 384 -> 98304 exact
  int l = idx / 49152;
  int r = idx - l * 49152;
  int j = r >> 7, k = r & 127;
  float v;
  if (j < 128)      v = Wmi[l*16384 + j*128 + k] + Wsh[l*16384 + j*128 + k];
  else if (j < 256) v = Wmo[l*16384 + (j-128)*128 + k] + Wsh[l*16384 + (j-128)*128 + k];
  else              v = Wu[l*16384 + (j-256)*128 + k];
  Wcat[idx] = f2bf(v);
}

// ---------------- partition phase A: per-chunk bucket histogram ----------------
__global__ __launch_bounds__(256) void countA_kernel(const int* __restrict__ ei0,
                                                     const int* __restrict__ ei1,
                                                     const int* __restrict__ ei2,
                                                     int* __restrict__ counts) {
  __shared__ int c[NB];
  int v = blockIdx.y, ch = blockIdx.x, tid = threadIdx.x;
  const int* dstp = ((v == 0) ? ei0 : (v == 1) ? ei1 : ei2) + EE;
  for (int i = tid; i < NB; i += 256) c[i] = 0;
  __syncthreads();
  int s = ch * CHUNK, e = (s + CHUNK < EE) ? s + CHUNK : EE;
  for (int i = s + tid; i < e; i += 256) atomicAdd(&c[dstp[i] >> 9], 1);
  __syncthreads();
  for (int b = tid; b < NB; b += 256) counts[(v * NB + b) * NCH + ch] = c[b];
}

// ---------------- scan (generalized length n) ----------------
__global__ __launch_bounds__(256) void scan1_kernel(const int* __restrict__ counts,
                                                    int* __restrict__ S,
                                                    int* __restrict__ bsums, int n) {
  __shared__ int sd[256];
  int t = threadIdx.x;
  int base = blockIdx.x * 1024 + t * 4;
  int4 v = make_int4(0, 0, 0, 0);
  if (base + 3 < n) {
    v = *(const int4*)&counts[base];
  } else {
    if (base + 0 < n) v.x = counts[base + 0];
    if (base + 1 < n) v.y = counts[base + 1];
    if (base + 2 < n) v.z = counts[base + 2];
    if (base + 3 < n) v.w = counts[base + 3];
  }
  int ts = v.x + v.y + v.z + v.w;
  sd[t] = ts;
  __syncthreads();
  for (int off = 1; off < 256; off <<= 1) {
    int xel = (t >= off) ? sd[t - off] : 0;
    __syncthreads();
    sd[t] += xel;
    __syncthreads();
  }
  int excl = sd[t] - ts;
  int o0 = excl, o1 = o0 + v.x, o2 = o1 + v.y, o3 = o2 + v.z;
  if (base + 0 < n) S[base + 0] = o0;
  if (base + 1 < n) S[base + 1] = o1;
  if (base + 2 < n) S[base + 2] = o2;
  if (base + 3 < n) S[base + 3] = o3;
  if (t == 255) bsums[blockIdx.x] = sd[255];
}

__global__ void scan2_kernel(int* __restrict__ bsums, int nb) {
  __shared__ int sd[512];
  int t = threadIdx.x;
  int v = (t < nb) ? bsums[t] : 0;
  sd[t] = v;
  __syncthreads();
  for (int off = 1; off < 512; off <<= 1) {
    int xel = (t >= off) ? sd[t - off] : 0;
    __syncthreads();
    sd[t] += xel;
    __syncthreads();
  }
  if (t < nb) bsums[t] = sd[t] - v;
}

__global__ __launch_bounds__(256) void scan3_kernel(int* __restrict__ S,
                                                    const int* __restrict__ bsums, int n) {
  int i = blockIdx.x * 256 + threadIdx.x;
  if (i < n) S[i] += bsums[i >> 10];
}

// ---------------- partition phase A: scatter into bucket-major runs ----------------
__global__ __launch_bounds__(256) void partA_kernel(const int* __restrict__ ei0,
                                                    const int* __restrict__ ei1,
                                                    const int* __restrict__ ei2,
                                                    const float* __restrict__ ew0,
                                                    const float* __restrict__ ew1,
                                                    const float* __restrict__ ew2,
                                                    const int* __restrict__ S,
                                                    int2* __restrict__ binned) {
  __shared__ int cur[NB];
  int v = blockIdx.y, ch = blockIdx.x, tid = threadIdx.x;
  const int* ei = (v == 0) ? ei0 : (v == 1) ? ei1 : ei2;
  const float* ew = (v == 0) ? ew0 : (v == 1) ? ew1 : ew2;
  for (int b = tid; b < NB; b += 256) cur[b] = S[(v * NB + b) * NCH + ch];
  __syncthreads();
  int s = ch * CHUNK, e = (s + CHUNK < EE) ? s + CHUNK : EE;
  for (int i = s + tid; i < e; i += 256) {
    int src = ei[i];
    int dst = ei[EE + i];
    float w = ew[i];
    int b = dst >> 9;
    int pos = atomicAdd(&cur[b], 1);
    binned[pos] = make_int2(src | ((dst & 511) << 17), __float_as_int(w));
  }
}

// ---------------- phase B: per-bucket local CSR + offs ----------------
__global__ __launch_bounds__(256) void buildB_kernel(const int2* __restrict__ binned,
                                                     const int* __restrict__ S,
                                                     unsigned* __restrict__ csr4,
                                                     int* __restrict__ offs) {
  __shared__ int2 recs[CAPB];   // 64 KB
  __shared__ int cnt[512];
  __shared__ int pref[512];
  __shared__ int sd[256];
  int gb = blockIdx.x, tid = threadIdx.x;
  int v = gb / NB, b = gb - v * NB;
  int base = S[gb * NCH];
  int next = (gb == 3 * NB - 1) ? 3 * EE : S[(gb + 1) * NCH];
  int n = next - base;
  for (int i = tid; i < 512; i += 256) cnt[i] = 0;
  int m = n < CAPB ? n : CAPB;
  for (int i = tid; i < m; i += 256) recs[i] = binned[base + i];
  __syncthreads();
  for (int i = tid; i < n; i += 256) {
    int2 r = (i < CAPB) ? recs[i] : binned[base + i];
    atomicAdd(&cnt[(r.x >> 17) & 511], 1);
  }
  __syncthreads();
  // exclusive scan over 512 with 256 threads (pairwise + Hillis-Steele)
  int c0 = cnt[2 * tid], c1 = cnt[2 * tid + 1];
  int ssum = c0 + c1;
  sd[tid] = ssum;
  __syncthreads();
  for (int off = 1; off < 256; off <<= 1) {
    int x = (tid >= off) ? sd[tid - off] : 0;
    __syncthreads();
    sd[tid] += x;
    __syncthreads();
  }
  int excl = sd[tid] - ssum;
  pref[2 * tid] = excl;
  pref[2 * tid + 1] = excl + c0;
  __syncthreads();
  int node0 = b * 512;
  for (int i = tid; i < 512; i += 256) {
    int node = node0 + i;
    if (node < NN) offs[v * NN + node] = base + pref[i];
  }
  if (gb == 0 && tid == 0) offs[3 * NN] = 3 * EE;
  for (int i = tid; i < 512; i += 256) cnt[i] = pref[i];   // cursors
  __syncthreads();
  for (int i = tid; i < n; i += 256) {
    int2 r = (i < CAPB) ? recs[i] : binned[base + i];
    int nl = (r.x >> 17) & 511;
    int p = atomicAdd(&cnt[nl], 1);
    float w = __int_as_float(r.y);
    unsigned wb = (unsigned)(unsigned short)f2bf(w);   // positive -> 15 bits
    csr4[base + p] = (wb << 17) | (unsigned)(r.x & 0x1FFFF);
  }
}

// ---------------- aggregate-first: gather h over 3 views -> g[3][N][128] ----------------
// One wave per node. Round-1 proven loop: coalesced record preload + shfl
// broadcast; all views gather from the SAME 25.6MB h table (3x smaller
// working set than tAll -> higher L2 hit rate on the gather path).
__global__ __launch_bounds__(256) void agg3_kernel(
    const short* __restrict__ h, const unsigned* __restrict__ csr4,
    const int* __restrict__ offs, short* __restrict__ g) {
  int gid = blockIdx.x * 256 + threadIdx.x;
  int v = gid >> 6;
  int lane = gid & 63;
  int f0 = lane * 2;

#pragma unroll
  for (int view = 0; view < 3; ++view) {
    int s = offs[view * NN + v];
    int e = offs[view * NN + v + 1];
    float accx = 0.f, accy = 0.f;
    for (int base = s; base < e; base += 64) {
      int cnt = e - base; if (cnt > 64) cnt = 64;
      int r = 0;
      if (lane < cnt) r = (int)csr4[base + lane];
      int j = 0;
      for (; j + 3 < cnt; j += 4) {
        unsigned r0 = (unsigned)__shfl(r, j);
        unsigned r1 = (unsigned)__shfl(r, j + 1);
        unsigned r2 = (unsigned)__shfl(r, j + 2);
        unsigned r3 = (unsigned)__shfl(r, j + 3);
        float w0 = __uint_as_float((r0 >> 17) << 16);
        float w1 = __uint_as_float((r1 >> 17) << 16);
        float w2 = __uint_as_float((r2 >> 17) << 16);
        float w3 = __uint_as_float((r3 >> 17) << 16);
        unsigned u0 = *(const unsigned*)&h[(size_t)(r0 & 0x1FFFF) * 128 + f0];
        unsigned u1 = *(const unsigned*)&h[(size_t)(r1 & 0x1FFFF) * 128 + f0];
        unsigned u2 = *(const unsigned*)&h[(size_t)(r2 & 0x1FFFF) * 128 + f0];
        unsigned u3 = *(const unsigned*)&h[(size_t)(r3 & 0x1FFFF) * 128 + f0];
        accx += w0 * bf_lo(u0) + w1 * bf_lo(u1) + w2 * bf_lo(u2) + w3 * bf_lo(u3);
        accy += w0 * bf_hi(u0) + w1 * bf_hi(u1) + w2 * bf_hi(u2) + w3 * bf_hi(u3);
      }
      for (; j < cnt; ++j) {
        unsigned r0 = (unsigned)__shfl(r, j);
        float w0 = __uint_as_float((r0 >> 17) << 16);
        unsigned u0 = *(const unsigned*)&h[(size_t)(r0 & 0x1FFFF) * 128 + f0];
        accx += w0 * bf_lo(u0);
        accy += w0 * bf_hi(u0);
      }
    }
    *(unsigned*)&g[(size_t)view * ((size_t)NN * 128) + (size_t)v * 128 + f0] =
        pack2(accx, accy);
  }
}

// ---------------- fused 3-view GEMM + combine + residual + leaky ----------------
// t'_v = (C_v ⊙ g_v) @ Wcat_v^T accumulated across views into ONE MFMA acc
// (C_v applied by row-scaling the A-tile during LDS staging). Epilogue adds
// Σ_v C_v[row]*bias_v[col] + constant + residual, leaky-ReLU, LDS-staged
// coalesced bf16 stores.
#define LW 136
__global__ __launch_bounds__(256) void mmc_kernel(
    const short* __restrict__ g, const short* __restrict__ WcatL,
    const float* __restrict__ b_mi, const float* __restrict__ b_mo,
    const float* __restrict__ b_si, const float* __restrict__ b_so,
    const float* __restrict__ b_u,
    const float* __restrict__ Cin, const float* __restrict__ Cou,
    const float* __restrict__ Cal,
    const float* __restrict__ cst, const short* __restrict__ h_prev,
    short* __restrict__ h_out) {
  __shared__ short As[128 * LW];
  __shared__ short Bs[128 * LW];
  __shared__ float cvs[3][128];
  __shared__ float bias[3][128];
  int tid = threadIdx.x;
  int rowbase = blockIdx.x * 128;

  if (tid < 128) {
    int r = tid;
    int gr = rowbase + r; if (gr >= NN) gr = NN - 1;
    cvs[0][r] = Cin[gr];
    cvs[1][r] = Cou[gr];
    cvs[2][r] = Cal[gr];
  } else {
    int c = tid - 128;
    bias[0][c] = b_mi[c] + b_si[c];
    bias[1][c] = b_mo[c] + b_so[c];
    bias[2][c] = b_u[c];
  }

  int w = tid >> 6, lane = tid & 63;
  int wr = (w >> 1) * 64, wc = (w & 1) * 64;
  int lrow = lane & 15, quad = lane >> 4;

  f32x4 comb[4][4];
#pragma unroll
  for (int mi = 0; mi < 4; ++mi)
#pragma unroll
    for (int ni = 0; ni < 4; ++ni) comb[mi][ni] = (f32x4){0.f, 0.f, 0.f, 0.f};

  for (int view = 0; view < 3; ++view) {
    __syncthreads();   // cvs/bias ready (view 0); prior view's LDS reads done
    const short* gv = g + (size_t)view * ((size_t)NN * 128);
    for (int idx = tid; idx < 2048; idx += 256) {
      int r = idx >> 4, c8 = (idx & 15) * 8;
      int gr = rowbase + r; if (gr >= NN) gr = NN - 1;
      float cv = cvs[view][r];
      int4 u = *(const int4*)&gv[(size_t)gr * 128 + c8];
      int4 o;
      o.x = pack2(cv * bf_lo((unsigned)u.x), cv * bf_hi((unsigned)u.x));
      o.y = pack2(cv * bf_lo((unsigned)u.y), cv * bf_hi((unsigned)u.y));
      o.z = pack2(cv * bf_lo((unsigned)u.z), cv * bf_hi((unsigned)u.z));
      o.w = pack2(cv * bf_lo((unsigned)u.w), cv * bf_hi((unsigned)u.w));
      *(int4*)&As[r * LW + c8] = o;
      *(int4*)&Bs[r * LW + c8] = *(const int4*)&WcatL[(view * 128 + r) * 128 + c8];
    }
    __syncthreads();

#pragma unroll
    for (int k0 = 0; k0 < 128; k0 += 32) {
      bf16x8 a[4], b[4];
#pragma unroll
      for (int mi = 0; mi < 4; ++mi)
        a[mi] = *(const bf16x8*)&As[(wr + mi * 16 + lrow) * LW + k0 + quad * 8];
#pragma unroll
      for (int ni = 0; ni < 4; ++ni)
        b[ni] = *(const bf16x8*)&Bs[(wc + ni * 16 + lrow) * LW + k0 + quad * 8];
#pragma unroll
      for (int mi = 0; mi < 4; ++mi)
#pragma unroll
        for (int ni = 0; ni < 4; ++ni)
          comb[mi][ni] = __builtin_amdgcn_mfma_f32_16x16x32_bf16(a[mi], b[ni], comb[mi][ni], 0, 0, 0);
    }
  }

  __syncthreads();   // all LDS reads done -> reuse Bs for output staging
#pragma unroll
  for (int mi = 0; mi < 4; ++mi) {
#pragma unroll
    for (int r = 0; r < 4; ++r) {
      int rl = wr + mi * 16 + quad * 4 + r;
      int row = rowbase + rl;
      int grow = (row < NN) ? row : NN - 1;
      float ci = cvs[0][rl], co = cvs[1][rl], ca = cvs[2][rl];
#pragma unroll
      for (int ni = 0; ni < 4; ++ni) {
        int cl = wc + ni * 16 + lrow;
        float val = comb[mi][ni][r]
                  + ci * bias[0][cl] + co * bias[1][cl] + ca * bias[2][cl]
                  + cst[(size_t)grow * 128 + cl]
                  + bfs(h_prev[(size_t)grow * 128 + cl]);
        val = val > 0.f ? val : 0.01f * val;
        Bs[rl * LW + cl] = f2bf(val);
      }
    }
  }
  __syncthreads();

  for (int idx = tid; idx < 2048; idx += 256) {
    int r = idx >> 4, c8 = (idx & 15) * 8;
    int row = rowbase + r;
    if (row < NN)
      *(int4*)&h_out[(size_t)row * 128 + c8] = *(const int4*)&Bs[r * LW + c8];
  }
}

// ---------------- fused decoder ----------------
__global__ __launch_bounds__(256) void dec_kernel(const short* __restrict__ h,
                                                  const float* __restrict__ Wd1,
                                                  const float* __restrict__ bd1,
                                                  const float* __restrict__ Wd2,
                                                  const float* __restrict__ bd2,
                                                  float* __restrict__ out_logp,
                                                  float* __restrict__ out_emb) {
  __shared__ float Hs[32 * 128];
  __shared__ float W1t[64 * 66];
  __shared__ float W2t[64 * 66];
  __shared__ float Zs[32 * 68];
  int tid = threadIdx.x;
  int base = blockIdx.x * 32;

  for (int idx = tid; idx < 2048; idx += 256) {
    unsigned u = *(const unsigned*)&h[(size_t)base * 128 + idx * 2];
    Hs[idx * 2] = bf_lo(u);
    Hs[idx * 2 + 1] = bf_hi(u);
  }
  for (int idx = tid; idx < 4096; idx += 256) {
    int c = idx >> 6, k = idx & 63;
    W2t[k * 66 + c] = Wd2[idx];
  }

  int j = tid & 63;
  int rg = tid >> 6;
  float zacc[8];
#pragma unroll
  for (int r = 0; r < 8; ++r) zacc[r] = 0.f;

  for (int kk = 0; kk < 128; kk += 64) {
    __syncthreads();
    for (int idx = tid; idx < 4096; idx += 256) {
      int jj = idx >> 6, k = idx & 63;
      W1t[k * 66 + jj] = Wd1[jj * 128 + kk + k];
    }
    __syncthreads();
    for (int k = 0; k < 64; ++k) {
      float w = W1t[k * 66 + j];
#pragma unroll
      for (int r = 0; r < 8; ++r) zacc[r] += Hs[(rg * 8 + r) * 128 + kk + k] * w;
    }
  }
  float b1 = bd1[j];
#pragma unroll
  for (int r = 0; r < 8; ++r) {
    float z = zacc[r] + b1;
    Zs[(rg * 8 + r) * 68 + j] = z > 0.f ? z : 0.f;
  }
  __syncthreads();

  float b2 = bd2[j];
  float lg[8];
#pragma unroll
  for (int i = 0; i < 8; ++i) lg[i] = b2;
  for (int k = 0; k < 64; ++k) {
    float w = W2t[k * 66 + j];
#pragma unroll
    for (int i = 0; i < 8; ++i) lg[i] += Zs[(rg + 4 * i) * 68 + k] * w;
  }

#pragma unroll
  for (int i = 0; i < 8; ++i) {
    float m = lg[i];
    for (int d = 1; d < 64; d <<= 1) m = fmaxf(m, __shfl_xor(m, d));
    float s = expf(lg[i] - m);
    for (int d = 1; d < 64; d <<= 1) s += __shfl_xor(s, d);
    float lp = lg[i] - m - logf(s);
    out_logp[(size_t)(base + rg + 4 * i) * 64 + j] = lp;
  }

#pragma unroll
  for (int i = 0; i < 8; ++i) {
    int r = rg + 4 * i;
    float v1 = Hs[r * 128 + j];
    float v2 = Hs[r * 128 + 64 + j];
    float ss = v1 * v1 + v2 * v2;
    for (int d = 1; d < 64; d <<= 1) ss += __shfl_xor(ss, d);
    float nrm = sqrtf(ss);
    float sc = 1.f / fmaxf(nrm, 1e-12f);
    size_t o = (size_t)(base + r) * 128;
    out_emb[o + j] = v1 * sc;
    out_emb[o + 64 + j] = v2 * sc;
  }
}

extern "C" void kernel_launch(void* const* d_in, const int* in_sizes, int n_in,
                              void* d_out, int out_size, void* d_ws, size_t ws_size,
                              hipStream_t stream) {
  const float* x   = (const float*)d_in[0];
  const int* eiI   = (const int*)d_in[1];
  const float* ewI = (const float*)d_in[2];
  const int* eiO   = (const int*)d_in[3];
  const float* ewO = (const float*)d_in[4];
  const int* eiU   = (const int*)d_in[5];
  const float* ewU = (const float*)d_in[6];
  const float* pe  = (const float*)d_in[7];
  const float* Wmi = (const float*)d_in[8];
  const float* Wmo = (const float*)d_in[9];
  const float* Wsh = (const float*)d_in[10];
  const float* Wu  = (const float*)d_in[11];
  const float* bmi = (const float*)d_in[12];
  const float* bmo = (const float*)d_in[13];
  const float* bsi = (const float*)d_in[14];
  const float* bso = (const float*)d_in[15];
  const float* bu  = (const float*)d_in[16];
  const float* Cin = (const float*)d_in[17];
  const float* Cou = (const float*)d_in[18];
  const float* Cal = (const float*)d_in[19];
  const float* cst = (const float*)d_in[20];
  const float* Wd1 = (const float*)d_in[21];
  const float* bd1 = (const float*)d_in[22];
  const float* Wd2 = (const float*)d_in[23];
  const float* bd2 = (const float*)d_in[24];

  const size_t ND = (size_t)NN * DD;   // 12,800,000
  short* wsS = (short*)d_ws;
  short* hA   = wsS;                    // ND shorts
  short* hB   = hA + ND;                // ND
  short* g    = hB + ND;                // 3*ND (aggregated features per view)
  short* Wcat = g + 3 * ND;             // 98304 shorts
  int2* binned   = (int2*)(Wcat + 98304);          // 3E int2 (24 MB)
  unsigned* csr4 = (unsigned*)(binned + (size_t)3 * EE); // 3E uint (12 MB)
  int* S      = (int*)(csr4 + (size_t)3 * EE);     // SLOTS ints
  int* bsums  = S + SLOTS + 4;                     // scan block sums (<=512)
  int* offs   = bsums + 512;                       // 3N+1

  pe_kernel<<<6250, 256, 0, stream>>>(x, pe, hA);
  wprep_kernel<<<384, 256, 0, stream>>>(Wmi, Wmo, Wsh, Wu, Wcat);

  dim3 chGrid(NCH, 3);
  countA_kernel<<<chGrid, 256, 0, stream>>>(eiI, eiO, eiU, S);   // S holds raw counts first
  const int nb1 = (SLOTS + 1023) / 1024;   // 141
  scan1_kernel<<<nb1, 256, 0, stream>>>(S, S, bsums, SLOTS);     // in-place exclusive (block-local)
  scan2_kernel<<<1, 512, 0, stream>>>(bsums, nb1);
  scan3_kernel<<<(SLOTS + 255) / 256, 256, 0, stream>>>(S, bsums, SLOTS);
  partA_kernel<<<chGrid, 256, 0, stream>>>(eiI, eiO, eiU, ewI, ewO, ewU, S, binned);
  buildB_kernel<<<3 * NB, 256, 0, stream>>>(binned, S, csr4, offs);

  const short* hin = hA;
  short* hout = hB;
  dim3 mmGrid((NN + 127) / 128);   // 782 blocks
  for (int l = 0; l < 2; ++l) {
    agg3_kernel<<<25000, 256, 0, stream>>>(hin, csr4, offs, g);
    mmc_kernel<<<mmGrid, 256, 0, stream>>>(g, Wcat + l * 49152,
                                           bmi + l * DD, bmo + l * DD,
                                           bsi + l * DD, bso + l * DD, bu + l * DD,
                                           Cin + l * NN, Cou + l * NN, Cal + l * NN,
                                           cst + (size_t)l * ND, hin, hout);
    short* tmp = (short*)hin;
    hin = hout;
    hout = tmp;
  }

  float* out_logp = (float*)d_out;
  float* out_emb = out_logp + (size_t)NN * CLS;
  dec_kernel<<<3125, 256, 0, stream>>>(hin, Wd1, bd1, Wd2, bd2, out_logp, out_emb);
}

// Round 4
// 764.402 us; speedup vs baseline: 1.0849x; 1.0740x over previous
//
#include <hip/hip_runtime.h>
#include <math.h>

#define NN 100000
#define EE 1000000
#define DD 128
#define CLS 64

#define NB 196        // destination buckets per view (512 nodes each)
#define CHUNK 4096    // edges per partition workgroup
#define NCH 245       // ceil(EE / CHUNK)
#define SLOTS (3 * NB * NCH)   // 144060
#define CAPB 8192     // LDS record cache in buildB

typedef short bf16x8 __attribute__((ext_vector_type(8)));
typedef float f32x4 __attribute__((ext_vector_type(4)));

static __device__ __forceinline__ short f2bf(float f) {
  union { float f; unsigned u; } v; v.f = f;
  unsigned r = v.u + 0x7FFF + ((v.u >> 16) & 1);   // RNE
  return (short)(r >> 16);
}
static __device__ __forceinline__ unsigned pack2(float a, float b) {
  return ((unsigned)(unsigned short)f2bf(b) << 16) | (unsigned short)f2bf(a);
}
static __device__ __forceinline__ float bf_lo(unsigned u) {
  union { unsigned u; float f; } v; v.u = u << 16; return v.f;
}
static __device__ __forceinline__ float bf_hi(unsigned u) {
  union { unsigned u; float f; } v; v.u = u & 0xffff0000u; return v.f;
}
static __device__ __forceinline__ float bfs(short s) {
  union { unsigned u; float f; } v; v.u = ((unsigned)(unsigned short)s) << 16; return v.f;
}

// ---------------- PE add: h = bf16(x + pe), 8 elems/thread ----------------
__global__ __launch_bounds__(256) void pe_kernel(const float* __restrict__ x,
                                                 const float* __restrict__ pe,
                                                 short* __restrict__ h) {
  int idx8 = blockIdx.x * 256 + threadIdx.x;   // grid 6250 -> 1.6M exact
  int d0 = (idx8 & 15) * 8;
  float4 a = *(const float4*)&x[(size_t)idx8 * 8];
  float4 b = *(const float4*)&x[(size_t)idx8 * 8 + 4];
  float4 pa = *(const float4*)&pe[d0];
  float4 pb = *(const float4*)&pe[d0 + 4];
  int4 o;
  o.x = pack2(a.x + pa.x, a.y + pa.y);
  o.y = pack2(a.z + pa.z, a.w + pa.w);
  o.z = pack2(b.x + pb.x, b.y + pb.y);
  o.w = pack2(b.z + pb.z, b.w + pb.w);
  *(int4*)&h[(size_t)idx8 * 8] = o;
}

// ---------------- weight prep ----------------
__global__ __launch_bounds__(256) void wprep_kernel(const float* __restrict__ Wmi,
                                                    const float* __restrict__ Wmo,
                                                    const float* __restrict__ Wsh,
                                                    const float* __restrict__ Wu,
                                                    short* __restrict__ Wcat) {
  int idx = blockIdx.x * 256 + threadIdx.x;   // grid 384 -> 98304 exact
  int l = idx / 49152;
  int r = idx - l * 49152;
  int j = r >> 7, k = r & 127;
  float v;
  if (j < 128)      v = Wmi[l*16384 + j*128 + k] + Wsh[l*16384 + j*128 + k];
  else if (j < 256) v = Wmo[l*16384 + (j-128)*128 + k] + Wsh[l*16384 + (j-128)*128 + k];
  else              v = Wu[l*16384 + (j-256)*128 + k];
  Wcat[idx] = f2bf(v);
}

// ---------------- partition phase A: per-chunk bucket histogram ----------------
__global__ __launch_bounds__(256) void countA_kernel(const int* __restrict__ ei0,
                                                     const int* __restrict__ ei1,
                                                     const int* __restrict__ ei2,
                                                     int* __restrict__ counts) {
  __shared__ int c[NB];
  int v = blockIdx.y, ch = blockIdx.x, tid = threadIdx.x;
  const int* dstp = ((v == 0) ? ei0 : (v == 1) ? ei1 : ei2) + EE;
  for (int i = tid; i < NB; i += 256) c[i] = 0;
  __syncthreads();
  int s = ch * CHUNK, e = (s + CHUNK < EE) ? s + CHUNK : EE;
  for (int i = s + tid; i < e; i += 256) atomicAdd(&c[dstp[i] >> 9], 1);
  __syncthreads();
  for (int b = tid; b < NB; b += 256) counts[(v * NB + b) * NCH + ch] = c[b];
}

// ---------------- scan (generalized length n) ----------------
__global__ __launch_bounds__(256) void scan1_kernel(const int* __restrict__ counts,
                                                    int* __restrict__ S,
                                                    int* __restrict__ bsums, int n) {
  __shared__ int sd[256];
  int t = threadIdx.x;
  int base = blockIdx.x * 1024 + t * 4;
  int4 v = make_int4(0, 0, 0, 0);
  if (base + 3 < n) {
    v = *(const int4*)&counts[base];
  } else {
    if (base + 0 < n) v.x = counts[base + 0];
    if (base + 1 < n) v.y = counts[base + 1];
    if (base + 2 < n) v.z = counts[base + 2];
    if (base + 3 < n) v.w = counts[base + 3];
  }
  int ts = v.x + v.y + v.z + v.w;
  sd[t] = ts;
  __syncthreads();
  for (int off = 1; off < 256; off <<= 1) {
    int xel = (t >= off) ? sd[t - off] : 0;
    __syncthreads();
    sd[t] += xel;
    __syncthreads();
  }
  int excl = sd[t] - ts;
  int o0 = excl, o1 = o0 + v.x, o2 = o1 + v.y, o3 = o2 + v.z;
  if (base + 0 < n) S[base + 0] = o0;
  if (base + 1 < n) S[base + 1] = o1;
  if (base + 2 < n) S[base + 2] = o2;
  if (base + 3 < n) S[base + 3] = o3;
  if (t == 255) bsums[blockIdx.x] = sd[255];
}

__global__ void scan2_kernel(int* __restrict__ bsums, int nb) {
  __shared__ int sd[512];
  int t = threadIdx.x;
  int v = (t < nb) ? bsums[t] : 0;
  sd[t] = v;
  __syncthreads();
  for (int off = 1; off < 512; off <<= 1) {
    int xel = (t >= off) ? sd[t - off] : 0;
    __syncthreads();
    sd[t] += xel;
    __syncthreads();
  }
  if (t < nb) bsums[t] = sd[t] - v;
}

__global__ __launch_bounds__(256) void scan3_kernel(int* __restrict__ S,
                                                    const int* __restrict__ bsums, int n) {
  int i = blockIdx.x * 256 + threadIdx.x;
  if (i < n) S[i] += bsums[i >> 10];
}

// ---------------- partition phase A: scatter into bucket-major runs ----------------
__global__ __launch_bounds__(256) void partA_kernel(const int* __restrict__ ei0,
                                                    const int* __restrict__ ei1,
                                                    const int* __restrict__ ei2,
                                                    const float* __restrict__ ew0,
                                                    const float* __restrict__ ew1,
                                                    const float* __restrict__ ew2,
                                                    const int* __restrict__ S,
                                                    int2* __restrict__ binned) {
  __shared__ int cur[NB];
  int v = blockIdx.y, ch = blockIdx.x, tid = threadIdx.x;
  const int* ei = (v == 0) ? ei0 : (v == 1) ? ei1 : ei2;
  const float* ew = (v == 0) ? ew0 : (v == 1) ? ew1 : ew2;
  for (int b = tid; b < NB; b += 256) cur[b] = S[(v * NB + b) * NCH + ch];
  __syncthreads();
  int s = ch * CHUNK, e = (s + CHUNK < EE) ? s + CHUNK : EE;
  for (int i = s + tid; i < e; i += 256) {
    int src = ei[i];
    int dst = ei[EE + i];
    float w = ew[i];
    int b = dst >> 9;
    int pos = atomicAdd(&cur[b], 1);
    binned[pos] = make_int2(src | ((dst & 511) << 17), __float_as_int(w));
  }
}

// ---------------- phase B: per-bucket local CSR + offs ----------------
__global__ __launch_bounds__(256) void buildB_kernel(const int2* __restrict__ binned,
                                                     const int* __restrict__ S,
                                                     unsigned* __restrict__ csr4,
                                                     int* __restrict__ offs) {
  __shared__ int2 recs[CAPB];   // 64 KB
  __shared__ int cnt[512];
  __shared__ int pref[512];
  __shared__ int sd[256];
  int gb = blockIdx.x, tid = threadIdx.x;
  int v = gb / NB, b = gb - v * NB;
  int base = S[gb * NCH];
  int next = (gb == 3 * NB - 1) ? 3 * EE : S[(gb + 1) * NCH];
  int n = next - base;
  for (int i = tid; i < 512; i += 256) cnt[i] = 0;
  int m = n < CAPB ? n : CAPB;
  for (int i = tid; i < m; i += 256) recs[i] = binned[base + i];
  __syncthreads();
  for (int i = tid; i < n; i += 256) {
    int2 r = (i < CAPB) ? recs[i] : binned[base + i];
    atomicAdd(&cnt[(r.x >> 17) & 511], 1);
  }
  __syncthreads();
  // exclusive scan over 512 with 256 threads (pairwise + Hillis-Steele)
  int c0 = cnt[2 * tid], c1 = cnt[2 * tid + 1];
  int ssum = c0 + c1;
  sd[tid] = ssum;
  __syncthreads();
  for (int off = 1; off < 256; off <<= 1) {
    int x = (tid >= off) ? sd[tid - off] : 0;
    __syncthreads();
    sd[tid] += x;
    __syncthreads();
  }
  int excl = sd[tid] - ssum;
  pref[2 * tid] = excl;
  pref[2 * tid + 1] = excl + c0;
  __syncthreads();
  int node0 = b * 512;
  for (int i = tid; i < 512; i += 256) {
    int node = node0 + i;
    if (node < NN) offs[v * NN + node] = base + pref[i];
  }
  if (gb == 0 && tid == 0) offs[3 * NN] = 3 * EE;
  for (int i = tid; i < 512; i += 256) cnt[i] = pref[i];   // cursors
  __syncthreads();
  for (int i = tid; i < n; i += 256) {
    int2 r = (i < CAPB) ? recs[i] : binned[base + i];
    int nl = (r.x >> 17) & 511;
    int p = atomicAdd(&cnt[nl], 1);
    float w = __int_as_float(r.y);
    unsigned wb = (unsigned)(unsigned short)f2bf(w);   // positive -> 15 bits
    csr4[base + p] = (wb << 17) | (unsigned)(r.x & 0x1FFFF);
  }
}

// ---------------- aggregate-first: gather h over 3 views -> g[3][N][128] ----------------
__global__ __launch_bounds__(256) void agg3_kernel(
    const short* __restrict__ h, const unsigned* __restrict__ csr4,
    const int* __restrict__ offs, short* __restrict__ g) {
  int gid = blockIdx.x * 256 + threadIdx.x;
  int v = gid >> 6;
  int lane = gid & 63;
  int f0 = lane * 2;

#pragma unroll
  for (int view = 0; view < 3; ++view) {
    int s = offs[view * NN + v];
    int e = offs[view * NN + v + 1];
    float accx = 0.f, accy = 0.f;
    for (int base = s; base < e; base += 64) {
      int cnt = e - base; if (cnt > 64) cnt = 64;
      int r = 0;
      if (lane < cnt) r = (int)csr4[base + lane];
      int j = 0;
      for (; j + 3 < cnt; j += 4) {
        unsigned r0 = (unsigned)__shfl(r, j);
        unsigned r1 = (unsigned)__shfl(r, j + 1);
        unsigned r2 = (unsigned)__shfl(r, j + 2);
        unsigned r3 = (unsigned)__shfl(r, j + 3);
        float w0 = __uint_as_float((r0 >> 17) << 16);
        float w1 = __uint_as_float((r1 >> 17) << 16);
        float w2 = __uint_as_float((r2 >> 17) << 16);
        float w3 = __uint_as_float((r3 >> 17) << 16);
        unsigned u0 = *(const unsigned*)&h[(size_t)(r0 & 0x1FFFF) * 128 + f0];
        unsigned u1 = *(const unsigned*)&h[(size_t)(r1 & 0x1FFFF) * 128 + f0];
        unsigned u2 = *(const unsigned*)&h[(size_t)(r2 & 0x1FFFF) * 128 + f0];
        unsigned u3 = *(const unsigned*)&h[(size_t)(r3 & 0x1FFFF) * 128 + f0];
        accx += w0 * bf_lo(u0) + w1 * bf_lo(u1) + w2 * bf_lo(u2) + w3 * bf_lo(u3);
        accy += w0 * bf_hi(u0) + w1 * bf_hi(u1) + w2 * bf_hi(u2) + w3 * bf_hi(u3);
      }
      for (; j < cnt; ++j) {
        unsigned r0 = (unsigned)__shfl(r, j);
        float w0 = __uint_as_float((r0 >> 17) << 16);
        unsigned u0 = *(const unsigned*)&h[(size_t)(r0 & 0x1FFFF) * 128 + f0];
        accx += w0 * bf_lo(u0);
        accy += w0 * bf_hi(u0);
      }
    }
    *(unsigned*)&g[(size_t)view * ((size_t)NN * 128) + (size_t)v * 128 + f0] =
        pack2(accx, accy);
  }
}

// ---------------- fused 3-view GEMM + combine + residual + leaky ----------------
#define LW 136
__global__ __launch_bounds__(256) void mmc_kernel(
    const short* __restrict__ g, const short* __restrict__ WcatL,
    const float* __restrict__ b_mi, const float* __restrict__ b_mo,
    const float* __restrict__ b_si, const float* __restrict__ b_so,
    const float* __restrict__ b_u,
    const float* __restrict__ Cin, const float* __restrict__ Cou,
    const float* __restrict__ Cal,
    const float* __restrict__ cst, const short* __restrict__ h_prev,
    short* __restrict__ h_out) {
  __shared__ short As[128 * LW];
  __shared__ short Bs[128 * LW];
  __shared__ float cvs[3][128];
  __shared__ float bias[3][128];
  int tid = threadIdx.x;
  int rowbase = blockIdx.x * 128;

  if (tid < 128) {
    int r = tid;
    int gr = rowbase + r; if (gr >= NN) gr = NN - 1;
    cvs[0][r] = Cin[gr];
    cvs[1][r] = Cou[gr];
    cvs[2][r] = Cal[gr];
  } else {
    int c = tid - 128;
    bias[0][c] = b_mi[c] + b_si[c];
    bias[1][c] = b_mo[c] + b_so[c];
    bias[2][c] = b_u[c];
  }

  int w = tid >> 6, lane = tid & 63;
  int wr = (w >> 1) * 64, wc = (w & 1) * 64;
  int lrow = lane & 15, quad = lane >> 4;

  f32x4 comb[4][4];
#pragma unroll
  for (int mi = 0; mi < 4; ++mi)
#pragma unroll
    for (int ni = 0; ni < 4; ++ni) comb[mi][ni] = (f32x4){0.f, 0.f, 0.f, 0.f};

  for (int view = 0; view < 3; ++view) {
    __syncthreads();   // cvs/bias ready (view 0); prior view's LDS reads done
    const short* gv = g + (size_t)view * ((size_t)NN * 128);
    for (int idx = tid; idx < 2048; idx += 256) {
      int r = idx >> 4, c8 = (idx & 15) * 8;
      int gr = rowbase + r; if (gr >= NN) gr = NN - 1;
      float cv = cvs[view][r];
      int4 u = *(const int4*)&gv[(size_t)gr * 128 + c8];
      int4 o;
      o.x = pack2(cv * bf_lo((unsigned)u.x), cv * bf_hi((unsigned)u.x));
      o.y = pack2(cv * bf_lo((unsigned)u.y), cv * bf_hi((unsigned)u.y));
      o.z = pack2(cv * bf_lo((unsigned)u.z), cv * bf_hi((unsigned)u.z));
      o.w = pack2(cv * bf_lo((unsigned)u.w), cv * bf_hi((unsigned)u.w));
      *(int4*)&As[r * LW + c8] = o;
      *(int4*)&Bs[r * LW + c8] = *(const int4*)&WcatL[(view * 128 + r) * 128 + c8];
    }
    __syncthreads();

#pragma unroll
    for (int k0 = 0; k0 < 128; k0 += 32) {
      bf16x8 a[4], b[4];
#pragma unroll
      for (int mi = 0; mi < 4; ++mi)
        a[mi] = *(const bf16x8*)&As[(wr + mi * 16 + lrow) * LW + k0 + quad * 8];
#pragma unroll
      for (int ni = 0; ni < 4; ++ni)
        b[ni] = *(const bf16x8*)&Bs[(wc + ni * 16 + lrow) * LW + k0 + quad * 8];
#pragma unroll
      for (int mi = 0; mi < 4; ++mi)
#pragma unroll
        for (int ni = 0; ni < 4; ++ni)
          comb[mi][ni] = __builtin_amdgcn_mfma_f32_16x16x32_bf16(a[mi], b[ni], comb[mi][ni], 0, 0, 0);
    }
  }

  __syncthreads();   // all LDS reads done -> reuse Bs for output staging
#pragma unroll
  for (int mi = 0; mi < 4; ++mi) {
#pragma unroll
    for (int r = 0; r < 4; ++r) {
      int rl = wr + mi * 16 + quad * 4 + r;
      int row = rowbase + rl;
      int grow = (row < NN) ? row : NN - 1;
      float ci = cvs[0][rl], co = cvs[1][rl], ca = cvs[2][rl];
#pragma unroll
      for (int ni = 0; ni < 4; ++ni) {
        int cl = wc + ni * 16 + lrow;
        float val = comb[mi][ni][r]
                  + ci * bias[0][cl] + co * bias[1][cl] + ca * bias[2][cl]
                  + cst[(size_t)grow * 128 + cl]
                  + bfs(h_prev[(size_t)grow * 128 + cl]);
        val = val > 0.f ? val : 0.01f * val;
        Bs[rl * LW + cl] = f2bf(val);
      }
    }
  }
  __syncthreads();

  for (int idx = tid; idx < 2048; idx += 256) {
    int r = idx >> 4, c8 = (idx & 15) * 8;
    int row = rowbase + r;
    if (row < NN)
      *(int4*)&h_out[(size_t)row * 128 + c8] = *(const int4*)&Bs[r * LW + c8];
  }
}

// ---------------- MFMA decoder: z=relu(h@Wd1^T+b1); logits=z@Wd2^T+b2 ----------------
// 128 rows/block. h (bf16) + Wd1/Wd2 (cast bf16) staged in LDS; two MFMA
// stages; emb from As; then As region reused as f32 logits buffer for the
// shfl-reduction log-softmax.
#define ZW 72
__global__ __launch_bounds__(256) void dec_kernel(const short* __restrict__ h,
                                                  const float* __restrict__ Wd1,
                                                  const float* __restrict__ bd1,
                                                  const float* __restrict__ Wd2,
                                                  const float* __restrict__ bd2,
                                                  float* __restrict__ out_logp,
                                                  float* __restrict__ out_emb) {
  __shared__ short As[128 * LW];    // 34816 B ; later reused as float Ls[128*68]
  __shared__ short B1s[64 * LW];    // 17408 B
  __shared__ short Zs[128 * ZW];    // 18432 B
  __shared__ short B2s[64 * ZW];    //  9216 B
  float* Ls = (float*)As;           // 128*68 floats = 34816 B (exact overlay)

  int tid = threadIdx.x;
  int rowbase = blockIdx.x * 128;

  // stage h rows (bf16, int4 copies)
  for (int idx = tid; idx < 2048; idx += 256) {
    int r = idx >> 4, c8 = (idx & 15) * 8;
    int gr = rowbase + r; if (gr >= NN) gr = NN - 1;
    *(int4*)&As[r * LW + c8] = *(const int4*)&h[(size_t)gr * 128 + c8];
  }
  // stage Wd1 -> bf16  (64x128)
  for (int idx = tid; idx < 2048; idx += 256) {
    int j = idx >> 5, k4 = (idx & 31) * 4;
    float4 wv = *(const float4*)&Wd1[j * 128 + k4];
    uint2 o; o.x = pack2(wv.x, wv.y); o.y = pack2(wv.z, wv.w);
    *(uint2*)&B1s[j * LW + k4] = o;
  }
  // stage Wd2 -> bf16  (64x64)
  for (int idx = tid; idx < 1024; idx += 256) {
    int j = idx >> 4, k4 = (idx & 15) * 4;
    float4 wv = *(const float4*)&Wd2[j * 64 + k4];
    uint2 o; o.x = pack2(wv.x, wv.y); o.y = pack2(wv.z, wv.w);
    *(uint2*)&B2s[j * ZW + k4] = o;
  }
  __syncthreads();

  int w = tid >> 6, lane = tid & 63;
  int wr = w * 32;                 // each wave: 32 rows, full N=64
  int lrow = lane & 15, quad = lane >> 4;

  float b1c[4], b2c[4];
#pragma unroll
  for (int ni = 0; ni < 4; ++ni) {
    b1c[ni] = bd1[ni * 16 + lrow];
    b2c[ni] = bd2[ni * 16 + lrow];
  }

  // ---- MFMA1: z = h @ Wd1^T ----
  f32x4 acc1[2][4];
#pragma unroll
  for (int mi = 0; mi < 2; ++mi)
#pragma unroll
    for (int ni = 0; ni < 4; ++ni) acc1[mi][ni] = (f32x4){0.f, 0.f, 0.f, 0.f};
#pragma unroll
  for (int k0 = 0; k0 < 128; k0 += 32) {
    bf16x8 a[2], b[4];
#pragma unroll
    for (int mi = 0; mi < 2; ++mi)
      a[mi] = *(const bf16x8*)&As[(wr + mi * 16 + lrow) * LW + k0 + quad * 8];
#pragma unroll
    for (int ni = 0; ni < 4; ++ni)
      b[ni] = *(const bf16x8*)&B1s[(ni * 16 + lrow) * LW + k0 + quad * 8];
#pragma unroll
    for (int mi = 0; mi < 2; ++mi)
#pragma unroll
      for (int ni = 0; ni < 4; ++ni)
        acc1[mi][ni] = __builtin_amdgcn_mfma_f32_16x16x32_bf16(a[mi], b[ni], acc1[mi][ni], 0, 0, 0);
  }
  // z = relu(acc1 + b1) -> bf16 Zs  (each wave writes only its own 32 rows)
#pragma unroll
  for (int mi = 0; mi < 2; ++mi)
#pragma unroll
    for (int ni = 0; ni < 4; ++ni)
#pragma unroll
      for (int r = 0; r < 4; ++r) {
        int rl = wr + mi * 16 + quad * 4 + r;
        int cl = ni * 16 + lrow;
        float z = acc1[mi][ni][r] + b1c[ni];
        Zs[rl * ZW + cl] = f2bf(z > 0.f ? z : 0.f);
      }
  __syncthreads();

  // ---- MFMA2: logits = z @ Wd2^T ----
  f32x4 acc2[2][4];
#pragma unroll
  for (int mi = 0; mi < 2; ++mi)
#pragma unroll
    for (int ni = 0; ni < 4; ++ni) acc2[mi][ni] = (f32x4){0.f, 0.f, 0.f, 0.f};
#pragma unroll
  for (int k0 = 0; k0 < 64; k0 += 32) {
    bf16x8 a[2], b[4];
#pragma unroll
    for (int mi = 0; mi < 2; ++mi)
      a[mi] = *(const bf16x8*)&Zs[(wr + mi * 16 + lrow) * ZW + k0 + quad * 8];
#pragma unroll
    for (int ni = 0; ni < 4; ++ni)
      b[ni] = *(const bf16x8*)&B2s[(ni * 16 + lrow) * ZW + k0 + quad * 8];
#pragma unroll
    for (int mi = 0; mi < 2; ++mi)
#pragma unroll
      for (int ni = 0; ni < 4; ++ni)
        acc2[mi][ni] = __builtin_amdgcn_mfma_f32_16x16x32_bf16(a[mi], b[ni], acc2[mi][ni], 0, 0, 0);
  }

  // ---- emb (reads As BEFORE it is overwritten by logits) ----
  int j = lane;   // feature pair (j, j+64)
  int rg = w;
#pragma unroll
  for (int i = 0; i < 32; ++i) {
    int r = rg + 4 * i;
    float v1 = bfs(As[r * LW + j]);
    float v2 = bfs(As[r * LW + 64 + j]);
    float ss = v1 * v1 + v2 * v2;
    for (int d = 1; d < 64; d <<= 1) ss += __shfl_xor(ss, d);
    float nrm = sqrtf(ss);
    float sc = 1.f / fmaxf(nrm, 1e-12f);
    int row = rowbase + r;
    if (row < NN) {
      size_t o = (size_t)row * 128;
      out_emb[o + j] = v1 * sc;
      out_emb[o + 64 + j] = v2 * sc;
    }
  }
  __syncthreads();   // emb done -> safe to overwrite As with logits

  // ---- write logits to LDS ----
#pragma unroll
  for (int mi = 0; mi < 2; ++mi)
#pragma unroll
    for (int ni = 0; ni < 4; ++ni)
#pragma unroll
      for (int r = 0; r < 4; ++r) {
        int rl = wr + mi * 16 + quad * 4 + r;
        int cl = ni * 16 + lrow;
        Ls[rl * 68 + cl] = acc2[mi][ni][r] + b2c[ni];
      }
  __syncthreads();

  // ---- log-softmax per row (64 cols across 64 lanes) ----
#pragma unroll
  for (int i = 0; i < 32; ++i) {
    int r = rg + 4 * i;
    float lg = Ls[r * 68 + j];
    float m = lg;
    for (int d = 1; d < 64; d <<= 1) m = fmaxf(m, __shfl_xor(m, d));
    float s = expf(lg - m);
    for (int d = 1; d < 64; d <<= 1) s += __shfl_xor(s, d);
    float lp = lg - m - logf(s);
    int row = rowbase + r;
    if (row < NN) out_logp[(size_t)row * 64 + j] = lp;
  }
}

extern "C" void kernel_launch(void* const* d_in, const int* in_sizes, int n_in,
                              void* d_out, int out_size, void* d_ws, size_t ws_size,
                              hipStream_t stream) {
  const float* x   = (const float*)d_in[0];
  const int* eiI   = (const int*)d_in[1];
  const float* ewI = (const float*)d_in[2];
  const int* eiO   = (const int*)d_in[3];
  const float* ewO = (const float*)d_in[4];
  const int* eiU   = (const int*)d_in[5];
  const float* ewU = (const float*)d_in[6];
  const float* pe  = (const float*)d_in[7];
  const float* Wmi = (const float*)d_in[8];
  const float* Wmo = (const float*)d_in[9];
  const float* Wsh = (const float*)d_in[10];
  const float* Wu  = (const float*)d_in[11];
  const float* bmi = (const float*)d_in[12];
  const float* bmo = (const float*)d_in[13];
  const float* bsi = (const float*)d_in[14];
  const float* bso = (const float*)d_in[15];
  const float* bu  = (const float*)d_in[16];
  const float* Cin = (const float*)d_in[17];
  const float* Cou = (const float*)d_in[18];
  const float* Cal = (const float*)d_in[19];
  const float* cst = (const float*)d_in[20];
  const float* Wd1 = (const float*)d_in[21];
  const float* bd1 = (const float*)d_in[22];
  const float* Wd2 = (const float*)d_in[23];
  const float* bd2 = (const float*)d_in[24];

  const size_t ND = (size_t)NN * DD;   // 12,800,000
  short* wsS = (short*)d_ws;
  short* hA   = wsS;                    // ND shorts
  short* hB   = hA + ND;                // ND
  short* g    = hB + ND;                // 3*ND (aggregated features per view)
  short* Wcat = g + 3 * ND;             // 98304 shorts
  int2* binned   = (int2*)(Wcat + 98304);          // 3E int2 (24 MB)
  unsigned* csr4 = (unsigned*)(binned + (size_t)3 * EE); // 3E uint (12 MB)
  int* S      = (int*)(csr4 + (size_t)3 * EE);     // SLOTS ints
  int* bsums  = S + SLOTS + 4;                     // scan block sums (<=512)
  int* offs   = bsums + 512;                       // 3N+1

  pe_kernel<<<6250, 256, 0, stream>>>(x, pe, hA);
  wprep_kernel<<<384, 256, 0, stream>>>(Wmi, Wmo, Wsh, Wu, Wcat);

  dim3 chGrid(NCH, 3);
  countA_kernel<<<chGrid, 256, 0, stream>>>(eiI, eiO, eiU, S);   // S holds raw counts first
  const int nb1 = (SLOTS + 1023) / 1024;   // 141
  scan1_kernel<<<nb1, 256, 0, stream>>>(S, S, bsums, SLOTS);     // in-place exclusive (block-local)
  scan2_kernel<<<1, 512, 0, stream>>>(bsums, nb1);
  scan3_kernel<<<(SLOTS + 255) / 256, 256, 0, stream>>>(S, bsums, SLOTS);
  partA_kernel<<<chGrid, 256, 0, stream>>>(eiI, eiO, eiU, ewI, ewO, ewU, S, binned);
  buildB_kernel<<<3 * NB, 256, 0, stream>>>(binned, S, csr4, offs);

  const short* hin = hA;
  short* hout = hB;
  dim3 mmGrid((NN + 127) / 128);   // 782 blocks
  for (int l = 0; l < 2; ++l) {
    agg3_kernel<<<25000, 256, 0, stream>>>(hin, csr4, offs, g);
    mmc_kernel<<<mmGrid, 256, 0, stream>>>(g, Wcat + l * 49152,
                                           bmi + l * DD, bmo + l * DD,
                                           bsi + l * DD, bso + l * DD, bu + l * DD,
                                           Cin + l * NN, Cou + l * NN, Cal + l * NN,
                                           cst + (size_t)l * ND, hin, hout);
    short* tmp = (short*)hin;
    hin = hout;
    hout = tmp;
  }

  float* out_logp = (float*)d_out;
  float* out_emb = out_logp + (size_t)NN * CLS;
  dec_kernel<<<mmGrid, 256, 0, stream>>>(hin, Wd1, bd1, Wd2, bd2, out_logp, out_emb);
}